// Round 2
// baseline (4132.375 us; speedup 1.0000x reference)
//
#include <hip/hip_runtime.h>

#define B_ 32
#define S_ 512
#define E_ 512
#define BS_ (B_*S_)

typedef __bf16 bf16x8 __attribute__((ext_vector_type(8)));
typedef float f32x4 __attribute__((ext_vector_type(4)));
typedef unsigned short u16x8 __attribute__((ext_vector_type(8)));

__device__ __forceinline__ unsigned short f2bf(float f){
  unsigned u = __float_as_uint(f);
  u += 0x7fffu + ((u>>16)&1u);
  return (unsigned short)(u>>16);
}
__device__ __forceinline__ float bf2f(unsigned short u){
  return __uint_as_float(((unsigned)u)<<16);
}
__device__ __forceinline__ float sigm(float x){ return 1.f/(1.f+__expf(-x)); }
__device__ __forceinline__ float tanh_f(float x){
  x = fminf(fmaxf(x,-15.f),15.f);
  float t=__expf(2.f*x); return (t-1.f)/(t+1.f);
}
__device__ __forceinline__ void gload_lds16(const void* g, void* l){
  __builtin_amdgcn_global_load_lds((const __attribute__((address_space(1))) unsigned int*)g,
                                   (__attribute__((address_space(3))) unsigned int*)l, 16, 0, 0);
}

// ---------------- cast / small kernels ----------------
__global__ void cast_bf16_k(const float* __restrict__ in, unsigned short* __restrict__ out, int n4){
  int i = blockIdx.x*256 + threadIdx.x;
  if (i < n4){
    const float4 v = *(const float4*)(in + (size_t)i*4);
    ushort4 o; o.x=f2bf(v.x); o.y=f2bf(v.y); o.z=f2bf(v.z); o.w=f2bf(v.w);
    *(ushort4*)(out + (size_t)i*4) = o;
  }
}
__global__ void addb_k(const float* __restrict__ a, const float* __restrict__ b, float* __restrict__ o, int n){
  int i = blockIdx.x*256 + threadIdx.x;
  if (i < n) o[i] = a[i] + b[i];
}
__global__ void sentinel_k(float* __restrict__ o){ o[0] = 1e9f; }

// ---------------- GEMM: C[M,N] = A[M,K](bf16) @ Bw[N,K]^T(bf16) + bias ----------------
template<int OUTF /*0=bf16,1=f32*/, bool RELU>
__global__ __launch_bounds__(256) void gemm_bt(const unsigned short* __restrict__ A,
    const unsigned short* __restrict__ Bw, const float* __restrict__ bias,
    void* __restrict__ Cout, int M, int N, int K){
  __shared__ unsigned short As[128*32];
  __shared__ unsigned short Bs[128*32];
  const int tid = threadIdx.x, lane = tid&63, wid = tid>>6;
  const int bm = blockIdx.y, bn = blockIdx.x;
  const int wr = wid>>1, wc = wid&1;
  const int r = lane&15, kq = lane>>4;
  f32x4 acc[4][4] = {};
  const int nkt = K>>5;
  for (int kt=0; kt<nkt; ++kt){
#pragma unroll
    for (int i=0;i<2;++i){
      int cid = i*256 + tid;
      int row = cid>>2, kc = cid&3;
      int gcol = (kt<<5) + kc*8;
      gload_lds16(A  + (size_t)(bm*128+row)*K + gcol, (char*)As + (i*256 + wid*64)*16);
      gload_lds16(Bw + (size_t)(bn*128+row)*K + gcol, (char*)Bs + (i*256 + wid*64)*16);
    }
    __syncthreads();
    bf16x8 af[4], bfr[4];
#pragma unroll
    for (int i=0;i<4;++i){
      af[i]  = *(const bf16x8*)(As + (wr*64 + i*16 + r)*32 + kq*8);
      bfr[i] = *(const bf16x8*)(Bs + (wc*64 + i*16 + r)*32 + kq*8);
    }
#pragma unroll
    for (int i=0;i<4;++i)
#pragma unroll
      for (int j=0;j<4;++j)
        acc[i][j] = __builtin_amdgcn_mfma_f32_16x16x32_bf16(af[i], bfr[j], acc[i][j], 0,0,0);
    __syncthreads();
  }
#pragma unroll
  for (int j=0;j<4;++j){
    int n = bn*128 + wc*64 + j*16 + r;
    float bv = bias[n];
#pragma unroll
    for (int i=0;i<4;++i){
      int m0 = bm*128 + wr*64 + i*16 + kq*4;
#pragma unroll
      for (int jj=0;jj<4;++jj){
        float v = acc[i][j][jj] + bv;
        if (RELU) v = fmaxf(v, 0.f);
        size_t idx = (size_t)(m0+jj)*N + n;
        if (OUTF==0) ((unsigned short*)Cout)[idx] = f2bf(v);
        else         ((float*)Cout)[idx] = v;
      }
    }
  }
}

// ---------------- fused flash attention ----------------
__global__ __launch_bounds__(256) void attn_k(const unsigned short* __restrict__ qkv,
                                              unsigned short* __restrict__ ctx){
  __shared__ unsigned short Qs[128*64];
  __shared__ unsigned short Ks[128*64];
  __shared__ unsigned short Vt[64*128];
  __shared__ unsigned short Ps[128*128];
  const int tid=threadIdx.x, lane=tid&63, wid=tid>>6;
  const int qt=blockIdx.x, bh=blockIdx.y, b=bh>>3, h=bh&7;
  const int r=lane&15, kq=lane>>4;
  const int q0=qt*128;
#pragma unroll
  for (int i=0;i<4;++i){
    int cid=i*256+tid; int row=cid>>3, dc=cid&7;
    u16x8 v = *(const u16x8*)(qkv + (size_t)(b*S_+q0+row)*1536 + h*64 + dc*8);
    int byte = (row*128 + dc*16) ^ ((row&7)<<4);
    *(u16x8*)((char*)Qs + byte) = v;
  }
  float m_run[2][4], l_run[2][4];
  f32x4 o_acc[2][4] = {};
#pragma unroll
  for (int a=0;a<2;++a)
#pragma unroll
    for (int j=0;j<4;++j){ m_run[a][j]=-1e30f; l_run[a][j]=0.f; }
  for (int kt=0; kt<4; ++kt){
#pragma unroll
    for (int i=0;i<4;++i){
      int cid=i*256+tid; int row=cid>>3, dc=cid&7;
      u16x8 v = *(const u16x8*)(qkv + (size_t)(b*S_+kt*128+row)*1536 + 512 + h*64 + dc*8);
      int byte = (row*128 + dc*16) ^ ((row&7)<<4);
      *(u16x8*)((char*)Ks + byte) = v;
    }
#pragma unroll
    for (int i=0;i<4;++i){
      int cid=i*256+tid; int sv=cid>>3, dc=cid&7;
      u16x8 v = *(const u16x8*)(qkv + (size_t)(b*S_+kt*128+sv)*1536 + 1024 + h*64 + dc*8);
#pragma unroll
      for (int e=0;e<8;++e){
        int d=dc*8+e;
        int byte = (d*256 + sv*2) ^ ((d&7)<<4);
        *(unsigned short*)((char*)Vt + byte) = (unsigned short)v[e];
      }
    }
    __syncthreads();
    f32x4 sa[2][8] = {};
#pragma unroll
    for (int dstep=0; dstep<2; ++dstep){
      int d0 = dstep*32 + kq*8;
      int q1 = wid*32 + r, q2 = wid*32 + 16 + r;
      bf16x8 a0 = *(const bf16x8*)((char*)Qs + ((q1*128 + d0*2) ^ ((q1&7)<<4)));
      bf16x8 a1 = *(const bf16x8*)((char*)Qs + ((q2*128 + d0*2) ^ ((q2&7)<<4)));
#pragma unroll
      for (int fk=0; fk<8; ++fk){
        int kc = fk*16 + r;
        bf16x8 bk = *(const bf16x8*)((char*)Ks + ((kc*128 + d0*2) ^ ((kc&7)<<4)));
        sa[0][fk] = __builtin_amdgcn_mfma_f32_16x16x32_bf16(a0, bk, sa[0][fk],0,0,0);
        sa[1][fk] = __builtin_amdgcn_mfma_f32_16x16x32_bf16(a1, bk, sa[1][fk],0,0,0);
      }
    }
#pragma unroll
    for (int fq=0; fq<2; ++fq){
#pragma unroll
      for (int j=0;j<4;++j){
        float mx = -1e30f;
#pragma unroll
        for (int fk=0;fk<8;++fk) mx = fmaxf(mx, sa[fq][fk][j]);
        mx *= 0.125f;
#pragma unroll
        for (int off=1; off<16; off<<=1) mx = fmaxf(mx, __shfl_xor(mx, off));
        float mn = fmaxf(m_run[fq][j], mx);
        float corr = __expf(m_run[fq][j] - mn);
        float ps = 0.f;
#pragma unroll
        for (int fk=0;fk<8;++fk){
          float p = __expf(sa[fq][fk][j]*0.125f - mn);
          sa[fq][fk][j] = p; ps += p;
        }
#pragma unroll
        for (int off=1; off<16; off<<=1) ps += __shfl_xor(ps, off);
        l_run[fq][j] = l_run[fq][j]*corr + ps;
        m_run[fq][j] = mn;
#pragma unroll
        for (int fd=0; fd<4; ++fd) o_acc[fq][fd][j] *= corr;
      }
    }
#pragma unroll
    for (int fq=0;fq<2;++fq)
#pragma unroll
      for (int fk=0;fk<8;++fk)
#pragma unroll
        for (int j=0;j<4;++j){
          int qr = wid*32 + fq*16 + kq*4 + j;
          int kc = fk*16 + r;
          int byte = (qr*256 + kc*2) ^ ((qr&7)<<4);
          *(unsigned short*)((char*)Ps + byte) = f2bf(sa[fq][fk][j]);
        }
#pragma unroll
    for (int kk=0;kk<4;++kk){
      int k0 = kk*32 + kq*8;
      bf16x8 pa[2];
#pragma unroll
      for (int fq=0;fq<2;++fq){
        int q = wid*32 + fq*16 + r;
        pa[fq] = *(const bf16x8*)((char*)Ps + ((q*256 + k0*2) ^ ((q&7)<<4)));
      }
#pragma unroll
      for (int fd=0; fd<4; ++fd){
        int d = fd*16 + r;
        bf16x8 bv = *(const bf16x8*)((char*)Vt + ((d*256 + k0*2) ^ ((d&7)<<4)));
        o_acc[0][fd] = __builtin_amdgcn_mfma_f32_16x16x32_bf16(pa[0], bv, o_acc[0][fd],0,0,0);
        o_acc[1][fd] = __builtin_amdgcn_mfma_f32_16x16x32_bf16(pa[1], bv, o_acc[1][fd],0,0,0);
      }
    }
    __syncthreads();
  }
#pragma unroll
  for (int fq=0;fq<2;++fq)
#pragma unroll
    for (int fd=0;fd<4;++fd)
#pragma unroll
      for (int j=0;j<4;++j){
        int qr = q0 + wid*32 + fq*16 + kq*4 + j;
        float v = o_acc[fq][fd][j] / l_run[fq][j];
        ctx[(size_t)(b*S_+qr)*512 + h*64 + fd*16 + r] = f2bf(v);
      }
}

// ---------------- LayerNorm(raw + res) ----------------
template<bool DUAL>
__global__ __launch_bounds__(64) void ln_k(const float* __restrict__ raw, const float* __restrict__ res,
    const float* __restrict__ gam, const float* __restrict__ bet,
    float* __restrict__ outf, unsigned short* __restrict__ outb){
  const int row=blockIdx.x, lane=threadIdx.x;
  const size_t base=(size_t)row*512 + lane*8;
  float v[8];
  {
    float4 a0=*(const float4*)(raw+base), a1=*(const float4*)(raw+base+4);
    float4 b0=*(const float4*)(res+base), b1=*(const float4*)(res+base+4);
    v[0]=a0.x+b0.x; v[1]=a0.y+b0.y; v[2]=a0.z+b0.z; v[3]=a0.w+b0.w;
    v[4]=a1.x+b1.x; v[5]=a1.y+b1.y; v[6]=a1.z+b1.z; v[7]=a1.w+b1.w;
  }
  float s=0.f;
#pragma unroll
  for (int k=0;k<8;++k) s+=v[k];
#pragma unroll
  for (int off=1;off<64;off<<=1) s+=__shfl_xor(s,off);
  float mu=s*(1.f/512.f);
  float q=0.f;
#pragma unroll
  for (int k=0;k<8;++k){ float d=v[k]-mu; q+=d*d; }
#pragma unroll
  for (int off=1;off<64;off<<=1) q+=__shfl_xor(q,off);
  float rs=rsqrtf(q*(1.f/512.f)+1e-5f);
  float gv[8], bv[8];
  *(float4*)gv=*(const float4*)(gam+lane*8); *(float4*)(gv+4)=*(const float4*)(gam+lane*8+4);
  *(float4*)bv=*(const float4*)(bet+lane*8); *(float4*)(bv+4)=*(const float4*)(bet+lane*8+4);
  float y[8];
#pragma unroll
  for (int k=0;k<8;++k) y[k]=(v[k]-mu)*rs*gv[k]+bv[k];
  *(float4*)(outf+base)   = make_float4(y[0],y[1],y[2],y[3]);
  *(float4*)(outf+base+4) = make_float4(y[4],y[5],y[6],y[7]);
  if (DUAL){
    u16x8 ob;
#pragma unroll
    for (int k=0;k<8;++k) ob[k]=f2bf(y[k]);
    *(u16x8*)(outb+base)=ob;
  }
}

// ---------------- persistent LSTM scan ----------------
// 32 WGs x 256 thr. WG owns 16 hidden units (64 W_hh rows in LDS, XOR-swizzled).
// Per step: gates[32b x 64col] = xpart(bf16) + h@Whh^T (MFMA), nonlin,
// hn -> hs via sc0sc1 stores, monotonic-counter agent barrier. c stays in regs.
__global__ __launch_bounds__(256,1) void lstm_k(const unsigned short* __restrict__ whh,
    const unsigned short* __restrict__ xpart, unsigned short* __restrict__ hs,
    float* __restrict__ hn_out, float* __restrict__ cn_out, unsigned* __restrict__ bar){
  __shared__ unsigned short Wsl[64*512];   // 64KB
  __shared__ unsigned short Hb[32*512];    // 32KB
  const int tid=threadIdx.x, lane=tid&63, wid=tid>>6;
  const int wg = blockIdx.x;
  const int r=lane&15, kq=lane>>4;
  const int c=r, gate=c&3, uo=(wid<<2)+(c>>2), unit=wg*16+uo;
#pragma unroll
  for (int i=0;i<16;++i){
    int ch=i*256+tid; int lc=ch>>6, kc=ch&63;
    int uoo=((lc>>4)<<2)+((lc&15)>>2), gg=lc&3;
    u16x8 v = *(const u16x8*)(whh + (size_t)(gg*512 + wg*16 + uoo)*512 + kc*8);
    int byte=(lc*1024+kc*16)^((lc&7)<<4);
    *(u16x8*)((char*)Wsl+byte)=v;
  }
  float cst[8]={0,0,0,0,0,0,0,0};
  float hlast[8]={0,0,0,0,0,0,0,0};
  __syncthreads();
  for (int t=0;t<512;++t){
    float xp[8];
#pragma unroll
    for (int s=0;s<8;++s){
      int bb=(s>>2)*16 + kq*4 + (s&3);
      xp[s]=bf2f(xpart[(size_t)(bb*512+t)*2048 + gate*512 + unit]);
    }
    if (t==0){
#pragma unroll
      for (int i=0;i<8;++i){
        int ch=i*256+tid; int bb=ch>>6, kc=ch&63;
        int byte=(bb*1024+kc*16)^((bb&7)<<4);
        u16x8 z={0,0,0,0,0,0,0,0};
        *(u16x8*)((char*)Hb+byte)=z;
      }
    } else {
#pragma unroll
      for (int i=0;i<8;++i){
        int ch=i*256+tid; int bb=ch>>6, kc=ch&63;
        const unsigned long long* gp=(const unsigned long long*)(hs+(size_t)(bb*512+(t-1))*512+kc*8);
        unsigned long long lo=__hip_atomic_load(gp,  __ATOMIC_RELAXED,__HIP_MEMORY_SCOPE_AGENT);
        unsigned long long hi=__hip_atomic_load(gp+1,__ATOMIC_RELAXED,__HIP_MEMORY_SCOPE_AGENT);
        int byte=(bb*1024+kc*16)^((bb&7)<<4);
        *(unsigned long long*)((char*)Hb+byte)=lo;
        *(unsigned long long*)((char*)Hb+byte+8)=hi;
      }
    }
    __syncthreads();
    f32x4 acc[2];
    acc[0][0]=xp[0]; acc[0][1]=xp[1]; acc[0][2]=xp[2]; acc[0][3]=xp[3];
    acc[1][0]=xp[4]; acc[1][1]=xp[5]; acc[1][2]=xp[6]; acc[1][3]=xp[7];
#pragma unroll
    for (int ki=0;ki<16;++ki){
      int k0=ki*32+kq*8;
      int b0=r, b1=16+r;
      bf16x8 a0=*(const bf16x8*)((char*)Hb+((b0*1024+k0*2)^((b0&7)<<4)));
      bf16x8 a1=*(const bf16x8*)((char*)Hb+((b1*1024+k0*2)^((b1&7)<<4)));
      int lc=wid*16+c;
      bf16x8 bw=*(const bf16x8*)((char*)Wsl+((lc*1024+k0*2)^((lc&7)<<4)));
      acc[0]=__builtin_amdgcn_mfma_f32_16x16x32_bf16(a0,bw,acc[0],0,0,0);
      acc[1]=__builtin_amdgcn_mfma_f32_16x16x32_bf16(a1,bw,acc[1],0,0,0);
    }
#pragma unroll
    for (int s=0;s<8;++s){
      float v=acc[s>>2][s&3];
      float n1=__shfl_xor(v,1), n2=__shfl_xor(v,2), n3=__shfl_xor(v,3);
      float g_[4];
      g_[gate]=v; g_[gate^1]=n1; g_[gate^2]=n2; g_[gate^3]=n3;
      float ig=sigm(g_[0]), fg=sigm(g_[1]), gg=tanh_f(g_[2]), og=sigm(g_[3]);
      float cn=fg*cst[s]+ig*gg; cst[s]=cn;
      float hn=og*tanh_f(cn); hlast[s]=hn;
      if (gate==0){
        int bb=(s>>2)*16+kq*4+(s&3);
        unsigned hv=(unsigned)f2bf(hn);
        unsigned long long addr=(unsigned long long)(hs+(size_t)(bb*512+t)*512+unit);
        asm volatile("global_store_short %0, %1, off sc0 sc1" :: "v"(addr), "v"(hv) : "memory");
      }
    }
    asm volatile("s_waitcnt vmcnt(0)" ::: "memory");
    __syncthreads();
    if (tid==0){
      __hip_atomic_fetch_add(bar,1u,__ATOMIC_RELEASE,__HIP_MEMORY_SCOPE_AGENT);
      unsigned target=(unsigned)(32*(t+1));
      while (__hip_atomic_load(bar,__ATOMIC_RELAXED,__HIP_MEMORY_SCOPE_AGENT)<target)
        __builtin_amdgcn_s_sleep(2);
    }
    __syncthreads();
  }
  if (gate==0){
#pragma unroll
    for (int s=0;s<8;++s){
      int bb=(s>>2)*16+kq*4+(s&3);
      hn_out[bb*512+unit]=hlast[s];
      cn_out[bb*512+unit]=cst[s];
    }
  }
}

// ---------------- launch ----------------
extern "C" void kernel_launch(void* const* d_in, const int* in_sizes, int n_in,
                              void* d_out, int out_size, void* d_ws, size_t ws_size,
                              hipStream_t stream) {
  const float* x          =(const float*)d_in[0];
  const float* in_proj_w  =(const float*)d_in[1];
  const float* in_proj_b  =(const float*)d_in[2];
  const float* out_proj_w =(const float*)d_in[3];
  const float* out_proj_b =(const float*)d_in[4];
  const float* ln_g       =(const float*)d_in[5];
  const float* ln_b       =(const float*)d_in[6];
  const float* w_ih       =(const float*)d_in[7];
  const float* w_hh       =(const float*)d_in[8];
  const float* b_ih       =(const float*)d_in[9];
  const float* b_hh       =(const float*)d_in[10];
  const float* fc_w1      =(const float*)d_in[11];
  const float* fc_b1      =(const float*)d_in[12];
  const float* fc_w2      =(const float*)d_in[13];
  const float* fc_b2      =(const float*)d_in[14];
  const float* fc_wo      =(const float*)d_in[15];
  const float* fc_bo      =(const float*)d_in[16];

  size_t off=0;
  auto A=[&](size_t b)->char*{ char* p=(char*)d_ws+off; off+=(b+255)&~(size_t)255; return p; };
  // weights (persist whole run): ~10.2 MB
  unsigned short* wqkv =(unsigned short*)A((size_t)1536*512*2);
  unsigned short* wout =(unsigned short*)A((size_t)512*512*2);
  unsigned short* wih  =(unsigned short*)A((size_t)2048*512*2);
  unsigned short* whh  =(unsigned short*)A((size_t)2048*512*2);
  unsigned short* w1   =(unsigned short*)A((size_t)1024*512*2);
  unsigned short* w2   =(unsigned short*)A((size_t)1024*1024*2);
  unsigned short* wo   =(unsigned short*)A((size_t)512*1024*2);
  float*          biasc=(float*)A(2048*4);
  unsigned*       bar  =(unsigned*)A(256);
  // regions (time-multiplexed)
  char* regA = A((size_t)BS_*512*2);        // 16MB: xb -> attn_outb -> hs
  char* regB = A((size_t)BS_*2048*2);       // 64MB: qkvb(48)+ctxb(16) -> xpart -> h1b(32)+h2b(32)
  char* regC = A((size_t)BS_*512*4);        // 32MB: attn_out (f32, persists to final LN)
  if (off > ws_size){ sentinel_k<<<1,1,0,stream>>>((float*)d_out); return; }

  unsigned short* xb        =(unsigned short*)regA;
  unsigned short* attn_outb =(unsigned short*)regA;
  unsigned short* hs        =(unsigned short*)regA;
  unsigned short* qkvb      =(unsigned short*)regB;
  unsigned short* ctxb      =(unsigned short*)(regB + (size_t)BS_*1536*2);
  unsigned short* xpart     =(unsigned short*)regB;
  unsigned short* h1b       =(unsigned short*)regB;
  unsigned short* h2b       =(unsigned short*)(regB + (size_t)BS_*1024*2);
  float*          attn_out  =(float*)regC;
  // d_out doubles as scratch: attn_raw (stages C-D), out_raw (stages G-H).
  // Both occupy [0, BS*512) floats; hn/cn tail [BS*512, BS*512+2*B*512) untouched by them.
  float* outp  =(float*)d_out;
  float* attn_raw = outp;
  float* out_raw  = outp;
  float* hn_out=outp + (size_t)BS_*512;
  float* cn_out=hn_out + (size_t)B_*512;

  auto cast=[&](const float* in, unsigned short* out, size_t n){
    int n4=(int)(n/4);
    cast_bf16_k<<<(n4+255)/256,256,0,stream>>>(in,out,n4);
  };
  cast(x, xb, (size_t)BS_*512);
  cast(in_proj_w, wqkv, (size_t)1536*512);
  cast(out_proj_w, wout, (size_t)512*512);
  cast(w_ih, wih, (size_t)2048*512);
  cast(w_hh, whh, (size_t)2048*512);
  cast(fc_w1, w1, (size_t)1024*512);
  cast(fc_w2, w2, (size_t)1024*1024);
  cast(fc_wo, wo, (size_t)512*1024);
  addb_k<<<8,256,0,stream>>>(b_ih,b_hh,biasc,2048);
  hipMemsetAsync(bar,0,256,stream);

  gemm_bt<0,false><<<dim3(12,128),256,0,stream>>>(xb,wqkv,in_proj_b,qkvb,BS_,1536,512);
  attn_k<<<dim3(4,256),256,0,stream>>>(qkvb,ctxb);
  gemm_bt<1,false><<<dim3(4,128),256,0,stream>>>(ctxb,wout,out_proj_b,attn_raw,BS_,512,512);
  ln_k<true><<<BS_,64,0,stream>>>(attn_raw,x,ln_g,ln_b,attn_out,attn_outb);
  gemm_bt<0,false><<<dim3(16,128),256,0,stream>>>(attn_outb,wih,biasc,xpart,BS_,2048,512);
  lstm_k<<<32,256,0,stream>>>(whh,xpart,hs,hn_out,cn_out,bar);
  gemm_bt<0,true><<<dim3(8,128),256,0,stream>>>(hs,w1,fc_b1,h1b,BS_,1024,512);
  gemm_bt<0,true><<<dim3(8,128),256,0,stream>>>(h1b,w2,fc_b2,h2b,BS_,1024,1024);
  gemm_bt<1,false><<<dim3(4,128),256,0,stream>>>(h2b,wo,fc_bo,out_raw,BS_,512,1024);
  ln_k<false><<<BS_,64,0,stream>>>(out_raw,attn_out,ln_g,ln_b,outp,nullptr);
}